// Round 7
// baseline (418.785 us; speedup 1.0000x reference)
//
#include <hip/hip_runtime.h>
#include <hip/hip_bf16.h>
#include <math.h>

// Problem constants
#define NB 256   // graphs
#define NN 2048  // nodes
#define NR 64    // roots
#define ND 64    // embed dim
#define NT 8     // node types
#define NTH 512  // threads per block (8 waves: one wave per node type)
#define NW 8     // waves per block
#define XP 136   // hs row stride in shorts (272 B: 16B-aligned rows, conflict-benign)

typedef __attribute__((ext_vector_type(8))) short short8;
typedef __attribute__((ext_vector_type(4))) float f32x4;

__device__ __forceinline__ unsigned short f2bf(float f) {
    unsigned u = __float_as_uint(f);
    return (unsigned short)((u + 0x7fffu + ((u >> 16) & 1u)) >> 16);
}

// Fast GELU: 0.5*v*(1+erf(v/sqrt2)); erf via Abramowitz-Stegun 7.1.26
// (|err| <= 1.5e-7 — invisible under bf16-weight quantization noise).
__device__ __forceinline__ float fast_gelu(float v) {
    const float x  = v * 0.70710678118654752f;
    const float ax = fabsf(x);
    const float t  = __builtin_amdgcn_rcpf(fmaf(0.3275911f, ax, 1.0f));
    float p = fmaf(1.061405429f, t, -1.453152027f);
    p = fmaf(p, t, 1.421413741f);
    p = fmaf(p, t, -0.284496736f);
    p = fmaf(p, t, 0.254829592f);
    p *= t;
    const float e       = exp2f(ax * ax * -1.4426950408889634f); // exp(-x^2)
    const float erf_abs = fmaf(-p, e, 1.0f);
    const float er      = copysignf(erf_abs, v);
    return 0.5f * v * (1.0f + er);
}

// ---------------------------------------------------------------------------
// Pre-kernel: transpose weights to [type][out][in] bf16 (RNE).
// ---------------------------------------------------------------------------
__global__ void convert_weights(const float* __restrict__ W1,
                                const float* __restrict__ W2,
                                unsigned short* __restrict__ w1t,
                                unsigned short* __restrict__ w2t) {
    int g = blockIdx.x * 256 + threadIdx.x;
    if (g < NT * 128 * 128) {
        int t = g >> 14, r = g & 16383, j = r >> 7, i = r & 127;
        w1t[g] = f2bf(W1[(t * 128 + i) * 128 + j]);
    }
    if (g < NT * 64 * 128) {
        int t = g >> 13, r = g & 8191, d = r >> 7, jj = r & 127;
        w2t[g] = f2bf(W2[(t * 128 + jj) * 64 + d]);
    }
}

// Inclusive block scan of arr[0..2048) via wave shuffles: 3 barriers.
__device__ __forceinline__ void block_scan2048(unsigned* __restrict__ arr,
                                               unsigned* __restrict__ csum,
                                               int w, int lane) {
    for (int c = w; c < 32; c += NW) {
        unsigned v = arr[c * 64 + lane];
        #pragma unroll
        for (int off = 1; off < 64; off <<= 1) {
            unsigned u = __shfl_up(v, off, 64);
            if (lane >= off) v += u;
        }
        arr[c * 64 + lane] = v;
        if (lane == 63) csum[c] = v;
    }
    __syncthreads();
    if (w == 0) {
        unsigned s = (lane < 32) ? csum[lane] : 0u;
        #pragma unroll
        for (int off = 1; off < 32; off <<= 1) {
            unsigned u = __shfl_up(s, off, 64);
            if (lane >= off) s += u;
        }
        if (lane < 32) csum[lane] = s;
    }
    __syncthreads();
    for (int c = w; c < 32; c += NW)
        if (c > 0) arr[c * 64 + lane] += csum[c - 1];
    __syncthreads();
}

// ---------------------------------------------------------------------------
// One block (512 thr, 8 waves) per graph. Wave w owns node type t=w and holds
// that type's full weight set in registers: zero weight loads in the level
// loop. Per level, wave w processes bucket key=L*8+w in 16-row chunks.
// Gather reads a bf16 embedding mirror (d_ws) when available: short8 loads,
// no f2bf on the load path. listP holds key-sorted parent pairs so the
// gather address chain is a single ds_read_b32.
// ---------------------------------------------------------------------------
__global__ __launch_bounds__(NTH, 2)
void dag_encoder_kernel(const float* __restrict__ roots,
                        const float* __restrict__ b1,
                        const float* __restrict__ b2,
                        const int*   __restrict__ idxs,
                        const int*   __restrict__ types,
                        float* __restrict__ out,
                        const unsigned short* __restrict__ w1t,
                        const unsigned short* __restrict__ w2t,
                        unsigned short* __restrict__ mir)   // bf16 mirror or null
{
    __shared__ unsigned int   depth[NN];        // 8 KB (reused as scatter cursors)
    __shared__ unsigned short keys[NN];         // 4 KB
    __shared__ unsigned int   scanA[NN];        // 8 KB (inclusive key-count scan)
    __shared__ unsigned short list[NN];         // 4 KB (nodes sorted by key)
    __shared__ unsigned int   listP[NN];        // 8 KB (parent pairs, key-sorted)
    __shared__ __align__(4) unsigned short parv[2 * NN];  // 8 KB (parent pairs)
    __shared__ unsigned int   csum[32];         // scan chunk sums
    __shared__ __align__(16) unsigned short hs[NW][16][XP];  // 34 KB
    __shared__ int s_maxd;

    const int b    = blockIdx.x;
    const int tid  = threadIdx.x;
    const int w    = tid >> 6;     // wave id == owned node type
    const int lane = tid & 63;
    const int q    = lane >> 4;
    const int l    = lane & 15;

    float* gbuf = out + (size_t)b * NN * ND;
    unsigned short* mirg = mir ? (mir + (size_t)b * NN * ND) : (unsigned short*)0;
    const int* gtyp = types + (size_t)b * NN;
    const int* gi   = idxs  + (size_t)b * NN * 2;

    // ---- roots -> gbuf (+mirror); parents -> LDS; depth init ----
    {
        const float4* r4 = (const float4*)(roots + (size_t)b * NR * ND);
        float4* o4 = (float4*)gbuf;
        for (int i = tid; i < NR * ND / 4; i += NTH) {
            const float4 v = r4[i];
            o4[i] = v;
            if (mirg) {
                unsigned lo = (unsigned)f2bf(v.x) | ((unsigned)f2bf(v.y) << 16);
                unsigned hi = (unsigned)f2bf(v.z) | ((unsigned)f2bf(v.w) << 16);
                *(uint2*)&mirg[i * 4] = make_uint2(lo, hi);
            }
        }
        for (int i = tid; i < 2 * NN; i += NTH) parv[i] = (unsigned short)gi[i];
        for (int i = tid; i < NN; i += NTH) depth[i] = (i < NR) ? 0u : 0xFFFFFFFFu;
        for (int i = tid; i < NN; i += NTH) scanA[i] = 0;
        if (tid == 0) s_maxd = 0;
    }
    __syncthreads();

    // ---- depth: single-wave propagation over 64-node groups ----
    // Parents of node n are < n, so groups resolve in ascending order; the
    // lowest unresolved node always has resolved parents -> <=64 iters/group.
    if (w == 0) {
        for (int g0 = NR; g0 < NN; g0 += 64) {
            const int n  = g0 + lane;
            const int p0 = parv[2 * n];
            const int p1 = parv[2 * n + 1];
            bool done = false;
            #pragma unroll 1
            for (int iter = 0; iter < 64; ++iter) {
                if (!done) {
                    const unsigned d0 = depth[p0];
                    const unsigned d1 = depth[p1];
                    if (d0 != 0xFFFFFFFFu && d1 != 0xFFFFFFFFu) {
                        depth[n] = 1u + (d0 > d1 ? d0 : d1);
                        done = true;
                    }
                }
                if (__all(done)) break;
                asm volatile("s_waitcnt lgkmcnt(0)" ::: "memory");
            }
        }
    }
    __syncthreads();

    // ---- keys + histogram + maxd ----
    {
        unsigned mloc = 0;
        for (int i = tid; i < NN; i += NTH) {
            if (i >= NR) {
                unsigned lv = depth[i]; if (lv > 255u) lv = 255u;
                if (lv > mloc) mloc = lv;
                int key = (int)lv * 8 + gtyp[i];
                keys[i] = (unsigned short)key;
                atomicAdd(&scanA[key], 1u);
            }
        }
        atomicMax(&s_maxd, (int)mloc);
    }
    __syncthreads();

    // ---- inclusive scan of bucket counts (in place) ----
    block_scan2048(scanA, csum, w, lane);

    // scatter cursors (exclusive offsets) -> depth (dead)
    for (int i = tid; i < NN; i += NTH) depth[i] = (i == 0) ? 0u : scanA[i - 1];
    __syncthreads();

    // ---- scatter nodes into list (sorted by key), parents into listP ----
    for (int i = tid; i < NN; i += NTH) {
        if (i >= NR) {
            unsigned p = atomicAdd(&depth[keys[i]], 1u);
            list[p]  = (unsigned short)i;
            listP[p] = ((const unsigned*)parv)[i];
        }
    }
    __syncthreads();

    // ---- preload this wave's type weights into registers (held all exec) ----
    short8 w1f[32];
    #pragma unroll
    for (int n0 = 0; n0 < 8; ++n0)
        #pragma unroll
        for (int kk = 0; kk < 4; ++kk)
            w1f[n0 * 4 + kk] = *(const short8*)(w1t +
                ((size_t)(w * 128 + n0 * 16 + l) * 128 + kk * 32 + q * 8));
    short8 w2f[16];
    #pragma unroll
    for (int n0 = 0; n0 < 4; ++n0)
        #pragma unroll
        for (int kk = 0; kk < 4; ++kk)
            w2f[n0 * 4 + kk] = *(const short8*)(w2t +
                ((size_t)(w * 64 + n0 * 16 + l) * 128 + kk * 32 + q * 8));

    // ---- execute levels: wave w handles bucket (L, type=w) ----
    const int maxd = s_maxd;
    for (int L = 1; L <= maxd; ++L) {
        const int key = L * 8 + w;
        const unsigned seg = scanA[key - 1];
        const int cnt = (int)(scanA[key] - seg);
        for (int r0 = 0; r0 < cnt; r0 += 16) {
            const int rows = min(16, cnt - r0);

            // ---- gather A-fragments direct to registers ----
            // A[row=l][k=kk*32+q*8+j]; x-row = concat(emb[p0], emb[p1]).
            const int rr = min(l, rows - 1);
            const unsigned pcat = listP[seg + r0 + rr];
            const int p0 = (int)(pcat & 0xFFFFu), p1 = (int)(pcat >> 16);

            short8 af[4];
            if (mirg) {
                // bf16 mirror: 4x 16B loads, no conversion
                const unsigned short* m0 = mirg + (size_t)p0 * 64 + q * 8;
                const unsigned short* m1 = mirg + (size_t)p1 * 64 + q * 8;
                af[0] = *(const short8*)(m0);
                af[1] = *(const short8*)(m0 + 32);
                af[2] = *(const short8*)(m1);
                af[3] = *(const short8*)(m1 + 32);
            } else {
                float4 ga[8];
                #pragma unroll
                for (int kk = 0; kk < 4; ++kk) {
                    const float* s = gbuf + (size_t)(kk < 2 ? p0 : p1) * 64 + (kk & 1) * 32 + q * 8;
                    ga[2 * kk]     = *(const float4*)s;
                    ga[2 * kk + 1] = *(const float4*)(s + 4);
                }
                #pragma unroll
                for (int kk = 0; kk < 4; ++kk) {
                    short8 v;
                    v[0] = (short)f2bf(ga[2 * kk].x);
                    v[1] = (short)f2bf(ga[2 * kk].y);
                    v[2] = (short)f2bf(ga[2 * kk].z);
                    v[3] = (short)f2bf(ga[2 * kk].w);
                    v[4] = (short)f2bf(ga[2 * kk + 1].x);
                    v[5] = (short)f2bf(ga[2 * kk + 1].y);
                    v[6] = (short)f2bf(ga[2 * kk + 1].z);
                    v[7] = (short)f2bf(ga[2 * kk + 1].w);
                    af[kk] = v;
                }
            }

            // ---- layer 1 (two 64-col halves; weights already in regs) ----
            #pragma unroll
            for (int h = 0; h < 2; ++h) {
                f32x4 c1[4];
                #pragma unroll
                for (int n0 = 0; n0 < 4; ++n0) c1[n0] = (f32x4){0.f, 0.f, 0.f, 0.f};
                #pragma unroll
                for (int kk = 0; kk < 4; ++kk)
                    #pragma unroll
                    for (int n0 = 0; n0 < 4; ++n0)
                        c1[n0] = __builtin_amdgcn_mfma_f32_16x16x32_bf16(
                            af[kk], w1f[(h * 4 + n0) * 4 + kk], c1[n0], 0, 0, 0);

                #pragma unroll
                for (int n0 = 0; n0 < 4; ++n0) {
                    const float bv = b1[w * 128 + (h * 4 + n0) * 16 + l];
                    #pragma unroll
                    for (int rg = 0; rg < 4; ++rg) {
                        const float v = c1[n0][rg] + bv;
                        hs[w][q * 4 + rg][(h * 4 + n0) * 16 + l] = f2bf(fast_gelu(v));
                    }
                }
            }
            // same-wave cross-lane LDS visibility
            asm volatile("s_waitcnt lgkmcnt(0)" ::: "memory");

            // ---- layer 2 ----
            short8 a2[4];
            #pragma unroll
            for (int kk = 0; kk < 4; ++kk)
                a2[kk] = *(const short8*)&hs[w][l][kk * 32 + q * 8];
            f32x4 c2[4];
            #pragma unroll
            for (int n0 = 0; n0 < 4; ++n0) c2[n0] = (f32x4){0.f, 0.f, 0.f, 0.f};
            #pragma unroll
            for (int kk = 0; kk < 4; ++kk)
                #pragma unroll
                for (int n0 = 0; n0 < 4; ++n0)
                    c2[n0] = __builtin_amdgcn_mfma_f32_16x16x32_bf16(
                        a2[kk], w2f[n0 * 4 + kk], c2[n0], 0, 0, 0);

            // ---- epilogue: +b2, scatter store fp32 (+bf16 mirror) ----
            #pragma unroll
            for (int n0 = 0; n0 < 4; ++n0) {
                const float bv2 = b2[w * 64 + n0 * 16 + l];
                #pragma unroll
                for (int rg = 0; rg < 4; ++rg) {
                    const int row = q * 4 + rg;
                    if (row < rows) {
                        const int nd = list[seg + r0 + row];
                        const float val = c2[n0][rg] + bv2;
                        gbuf[nd * 64 + n0 * 16 + l] = val;
                        if (mirg) mirg[nd * 64 + n0 * 16 + l] = f2bf(val);
                    }
                }
            }
        }
        __syncthreads();   // level boundary (drains stores before next gather)
    }
}

extern "C" void kernel_launch(void* const* d_in, const int* in_sizes, int n_in,
                              void* d_out, int out_size, void* d_ws, size_t ws_size,
                              hipStream_t stream) {
    const float* roots = (const float*)d_in[0];
    const float* W1    = (const float*)d_in[1];
    const float* b1    = (const float*)d_in[2];
    const float* W2    = (const float*)d_in[3];
    const float* b2    = (const float*)d_in[4];
    const int*   idxs  = (const int*)d_in[5];
    const int*   types = (const int*)d_in[6];
    float*       outp  = (float*)d_out;

    unsigned short* w1t = (unsigned short*)d_ws;        // 256 KB
    unsigned short* w2t = w1t + NT * 128 * 128;         // 128 KB
    const size_t wbytes = (size_t)(NT * 128 * 128 + NT * 64 * 128) * 2;
    const size_t mbytes = (size_t)NB * NN * ND * 2;     // 64 MB bf16 mirror
    unsigned short* mirp = (ws_size >= wbytes + mbytes)
        ? (unsigned short*)((char*)d_ws + wbytes) : (unsigned short*)0;

    convert_weights<<<dim3(512), dim3(256), 0, stream>>>(W1, W2, w1t, w2t);
    dag_encoder_kernel<<<dim3(NB), dim3(NTH), 0, stream>>>(
        roots, b1, b2, idxs, types, outp, w1t, w2t, mirp);
}

// Round 8
// 336.029 us; speedup vs baseline: 1.2463x; 1.2463x over previous
//
#include <hip/hip_runtime.h>
#include <hip/hip_bf16.h>
#include <math.h>

// Problem constants
#define NB 256   // graphs
#define NN 2048  // nodes
#define NR 64    // roots
#define ND 64    // embed dim
#define NT 8     // node types
#define NTH 512  // threads per block (8 waves: one wave per node type)
#define NW 8     // waves per block
#define XP 136   // hs row stride in shorts (272 B: 16B-aligned rows, conflict-benign)

typedef __attribute__((ext_vector_type(8))) short short8;
typedef __attribute__((ext_vector_type(4))) float f32x4;

__device__ __forceinline__ unsigned short f2bf(float f) {
    unsigned u = __float_as_uint(f);
    return (unsigned short)((u + 0x7fffu + ((u >> 16) & 1u)) >> 16);
}

// Packed RNE f32x2 -> bf16x2 (compiles to v_cvt_pk_bf16_f32; bit-identical
// to f2bf pairs).
__device__ __forceinline__ unsigned pk2bf(float a, float b) {
    __hip_bfloat162 h = __float22bfloat162_rn(float2{a, b});
    unsigned r; __builtin_memcpy(&r, &h, 4); return r;
}

// Fast GELU: 0.5*v*(1+erf(v/sqrt2)); erf via Abramowitz-Stegun 7.1.26
// (|err| <= 1.5e-7 — invisible under bf16-weight quantization noise).
__device__ __forceinline__ float fast_gelu(float v) {
    const float x  = v * 0.70710678118654752f;
    const float ax = fabsf(x);
    const float t  = __builtin_amdgcn_rcpf(fmaf(0.3275911f, ax, 1.0f));
    float p = fmaf(1.061405429f, t, -1.453152027f);
    p = fmaf(p, t, 1.421413741f);
    p = fmaf(p, t, -0.284496736f);
    p = fmaf(p, t, 0.254829592f);
    p *= t;
    const float e       = exp2f(ax * ax * -1.4426950408889634f); // exp(-x^2)
    const float erf_abs = fmaf(-p, e, 1.0f);
    const float er      = copysignf(erf_abs, v);
    return 0.5f * v * (1.0f + er);
}

// ---------------------------------------------------------------------------
// Pre-kernel: transpose weights to [type][out][in] bf16 (RNE).
// ---------------------------------------------------------------------------
__global__ void convert_weights(const float* __restrict__ W1,
                                const float* __restrict__ W2,
                                unsigned short* __restrict__ w1t,
                                unsigned short* __restrict__ w2t) {
    int g = blockIdx.x * 256 + threadIdx.x;
    if (g < NT * 128 * 128) {
        int t = g >> 14, r = g & 16383, j = r >> 7, i = r & 127;
        w1t[g] = f2bf(W1[(t * 128 + i) * 128 + j]);
    }
    if (g < NT * 64 * 128) {
        int t = g >> 13, r = g & 8191, d = r >> 7, jj = r & 127;
        w2t[g] = f2bf(W2[(t * 128 + jj) * 64 + d]);
    }
}

// Inclusive block scan of arr[0..2048) via wave shuffles: 3 barriers.
__device__ __forceinline__ void block_scan2048(unsigned* __restrict__ arr,
                                               unsigned* __restrict__ csum,
                                               int w, int lane) {
    for (int c = w; c < 32; c += NW) {
        unsigned v = arr[c * 64 + lane];
        #pragma unroll
        for (int off = 1; off < 64; off <<= 1) {
            unsigned u = __shfl_up(v, off, 64);
            if (lane >= off) v += u;
        }
        arr[c * 64 + lane] = v;
        if (lane == 63) csum[c] = v;
    }
    __syncthreads();
    if (w == 0) {
        unsigned s = (lane < 32) ? csum[lane] : 0u;
        #pragma unroll
        for (int off = 1; off < 32; off <<= 1) {
            unsigned u = __shfl_up(s, off, 64);
            if (lane >= off) s += u;
        }
        if (lane < 32) csum[lane] = s;
    }
    __syncthreads();
    for (int c = w; c < 32; c += NW)
        if (c > 0) arr[c * 64 + lane] += csum[c - 1];
    __syncthreads();
}

// ---------------------------------------------------------------------------
// One block (512 thr, 8 waves) per graph. Wave w owns node type t=w and holds
// that type's full weight set + biases in registers: zero weight/bias loads
// in the level loop. Per level, wave w processes bucket key=L*8+w in 16-row
// chunks. listP holds key-sorted parent pairs (one ds_read address chain).
// ---------------------------------------------------------------------------
__global__ __launch_bounds__(NTH, 2)
void dag_encoder_kernel(const float* __restrict__ roots,
                        const float* __restrict__ b1,
                        const float* __restrict__ b2,
                        const int*   __restrict__ idxs,
                        const int*   __restrict__ types,
                        float* __restrict__ out,
                        const unsigned short* __restrict__ w1t,
                        const unsigned short* __restrict__ w2t)
{
    __shared__ unsigned int   depth[NN];        // 8 KB (reused as scatter cursors)
    __shared__ unsigned short keys[NN];         // 4 KB
    __shared__ unsigned int   scanA[NN];        // 8 KB (inclusive key-count scan)
    __shared__ unsigned short list[NN];         // 4 KB (nodes sorted by key)
    __shared__ unsigned int   listP[NN];        // 8 KB (parent pairs, key-sorted)
    __shared__ __align__(4) unsigned short parv[2 * NN];  // 8 KB (parent pairs)
    __shared__ unsigned int   csum[32];         // scan chunk sums
    __shared__ __align__(16) unsigned short hs[NW][16][XP];  // 34 KB
    __shared__ int s_maxd;

    const int b    = blockIdx.x;
    const int tid  = threadIdx.x;
    const int w    = tid >> 6;     // wave id == owned node type
    const int lane = tid & 63;
    const int q    = lane >> 4;
    const int l    = lane & 15;

    float* gbuf = out + (size_t)b * NN * ND;
    const int* gtyp = types + (size_t)b * NN;
    const int* gi   = idxs  + (size_t)b * NN * 2;

    // ---- roots -> gbuf; parents -> LDS; depth init ----
    {
        const float4* r4 = (const float4*)(roots + (size_t)b * NR * ND);
        float4* o4 = (float4*)gbuf;
        for (int i = tid; i < NR * ND / 4; i += NTH) o4[i] = r4[i];
        for (int i = tid; i < 2 * NN; i += NTH) parv[i] = (unsigned short)gi[i];
        for (int i = tid; i < NN; i += NTH) depth[i] = (i < NR) ? 0u : 0xFFFFFFFFu;
        for (int i = tid; i < NN; i += NTH) scanA[i] = 0;
        if (tid == 0) s_maxd = 0;
    }
    __syncthreads();

    // ---- depth: single-wave propagation over 64-node groups ----
    // Parents of node n are < n, so groups resolve in ascending order; the
    // lowest unresolved node always has resolved parents -> <=64 iters/group.
    if (w == 0) {
        for (int g0 = NR; g0 < NN; g0 += 64) {
            const int n  = g0 + lane;
            const int p0 = parv[2 * n];
            const int p1 = parv[2 * n + 1];
            bool done = false;
            #pragma unroll 1
            for (int iter = 0; iter < 64; ++iter) {
                if (!done) {
                    const unsigned d0 = depth[p0];
                    const unsigned d1 = depth[p1];
                    if (d0 != 0xFFFFFFFFu && d1 != 0xFFFFFFFFu) {
                        depth[n] = 1u + (d0 > d1 ? d0 : d1);
                        done = true;
                    }
                }
                if (__all(done)) break;
                asm volatile("s_waitcnt lgkmcnt(0)" ::: "memory");
            }
        }
    }
    __syncthreads();

    // ---- keys + histogram + maxd ----
    {
        unsigned mloc = 0;
        for (int i = tid; i < NN; i += NTH) {
            if (i >= NR) {
                unsigned lv = depth[i]; if (lv > 255u) lv = 255u;
                if (lv > mloc) mloc = lv;
                int key = (int)lv * 8 + gtyp[i];
                keys[i] = (unsigned short)key;
                atomicAdd(&scanA[key], 1u);
            }
        }
        atomicMax(&s_maxd, (int)mloc);
    }
    __syncthreads();

    // ---- inclusive scan of bucket counts (in place) ----
    block_scan2048(scanA, csum, w, lane);

    // scatter cursors (exclusive offsets) -> depth (dead)
    for (int i = tid; i < NN; i += NTH) depth[i] = (i == 0) ? 0u : scanA[i - 1];
    __syncthreads();

    // ---- scatter nodes into list (sorted by key), parents into listP ----
    for (int i = tid; i < NN; i += NTH) {
        if (i >= NR) {
            unsigned p = atomicAdd(&depth[keys[i]], 1u);
            list[p]  = (unsigned short)i;
            listP[p] = ((const unsigned*)parv)[i];
        }
    }
    __syncthreads();

    // ---- preload this wave's type weights + biases into registers ----
    short8 w1f[32];
    #pragma unroll
    for (int n0 = 0; n0 < 8; ++n0)
        #pragma unroll
        for (int kk = 0; kk < 4; ++kk)
            w1f[n0 * 4 + kk] = *(const short8*)(w1t +
                ((size_t)(w * 128 + n0 * 16 + l) * 128 + kk * 32 + q * 8));
    short8 w2f[16];
    #pragma unroll
    for (int n0 = 0; n0 < 4; ++n0)
        #pragma unroll
        for (int kk = 0; kk < 4; ++kk)
            w2f[n0 * 4 + kk] = *(const short8*)(w2t +
                ((size_t)(w * 64 + n0 * 16 + l) * 128 + kk * 32 + q * 8));
    float bv1[8], bv2[4];
    #pragma unroll
    for (int n = 0; n < 8; ++n) bv1[n] = b1[w * 128 + n * 16 + l];
    #pragma unroll
    for (int n = 0; n < 4; ++n) bv2[n] = b2[w * 64 + n * 16 + l];

    // ---- execute levels: wave w handles bucket (L, type=w) ----
    const int maxd = s_maxd;
    for (int L = 1; L <= maxd; ++L) {
        const int key = L * 8 + w;
        const unsigned seg = scanA[key - 1];
        const int cnt = (int)(scanA[key] - seg);
        for (int r0 = 0; r0 < cnt; r0 += 16) {
            const int rows = min(16, cnt - r0);

            // ---- gather A-fragments direct to registers ----
            // A[row=l][k=kk*32+q*8+j]; x-row = concat(emb[p0], emb[p1]).
            const int rr = min(l, rows - 1);
            const unsigned pcat = listP[seg + r0 + rr];
            const int p0 = (int)(pcat & 0xFFFFu), p1 = (int)(pcat >> 16);

            float4 ga[8];
            #pragma unroll
            for (int kk = 0; kk < 4; ++kk) {
                const float* s = gbuf + (size_t)(kk < 2 ? p0 : p1) * 64 + (kk & 1) * 32 + q * 8;
                ga[2 * kk]     = *(const float4*)s;
                ga[2 * kk + 1] = *(const float4*)(s + 4);
            }
            short8 af[4];
            #pragma unroll
            for (int kk = 0; kk < 4; ++kk) {
                union { short8 s; unsigned u[4]; } v;
                v.u[0] = pk2bf(ga[2 * kk].x,     ga[2 * kk].y);
                v.u[1] = pk2bf(ga[2 * kk].z,     ga[2 * kk].w);
                v.u[2] = pk2bf(ga[2 * kk + 1].x, ga[2 * kk + 1].y);
                v.u[3] = pk2bf(ga[2 * kk + 1].z, ga[2 * kk + 1].w);
                af[kk] = v.s;
            }

            // ---- layer 1 (two 64-col halves; weights already in regs) ----
            #pragma unroll
            for (int h = 0; h < 2; ++h) {
                f32x4 c1[4];
                #pragma unroll
                for (int n0 = 0; n0 < 4; ++n0) c1[n0] = (f32x4){0.f, 0.f, 0.f, 0.f};
                #pragma unroll
                for (int kk = 0; kk < 4; ++kk)
                    #pragma unroll
                    for (int n0 = 0; n0 < 4; ++n0)
                        c1[n0] = __builtin_amdgcn_mfma_f32_16x16x32_bf16(
                            af[kk], w1f[(h * 4 + n0) * 4 + kk], c1[n0], 0, 0, 0);

                #pragma unroll
                for (int n0 = 0; n0 < 4; ++n0) {
                    const float bv = bv1[h * 4 + n0];
                    #pragma unroll
                    for (int rg = 0; rg < 4; ++rg) {
                        const float v = c1[n0][rg] + bv;
                        hs[w][q * 4 + rg][(h * 4 + n0) * 16 + l] = f2bf(fast_gelu(v));
                    }
                }
            }
            // same-wave cross-lane LDS visibility
            asm volatile("s_waitcnt lgkmcnt(0)" ::: "memory");

            // ---- layer 2 ----
            short8 a2[4];
            #pragma unroll
            for (int kk = 0; kk < 4; ++kk)
                a2[kk] = *(const short8*)&hs[w][l][kk * 32 + q * 8];
            f32x4 c2[4];
            #pragma unroll
            for (int n0 = 0; n0 < 4; ++n0) c2[n0] = (f32x4){0.f, 0.f, 0.f, 0.f};
            #pragma unroll
            for (int kk = 0; kk < 4; ++kk)
                #pragma unroll
                for (int n0 = 0; n0 < 4; ++n0)
                    c2[n0] = __builtin_amdgcn_mfma_f32_16x16x32_bf16(
                        a2[kk], w2f[n0 * 4 + kk], c2[n0], 0, 0, 0);

            // ---- epilogue: +b2, scatter store ----
            #pragma unroll
            for (int n0 = 0; n0 < 4; ++n0) {
                const float bv = bv2[n0];
                #pragma unroll
                for (int rg = 0; rg < 4; ++rg) {
                    const int row = q * 4 + rg;
                    if (row < rows) {
                        const int nd = list[seg + r0 + row];
                        gbuf[nd * 64 + n0 * 16 + l] = c2[n0][rg] + bv;
                    }
                }
            }
        }
        __syncthreads();   // level boundary (drains stores before next gather)
    }
}

extern "C" void kernel_launch(void* const* d_in, const int* in_sizes, int n_in,
                              void* d_out, int out_size, void* d_ws, size_t ws_size,
                              hipStream_t stream) {
    const float* roots = (const float*)d_in[0];
    const float* W1    = (const float*)d_in[1];
    const float* b1    = (const float*)d_in[2];
    const float* W2    = (const float*)d_in[3];
    const float* b2    = (const float*)d_in[4];
    const int*   idxs  = (const int*)d_in[5];
    const int*   types = (const int*)d_in[6];
    float*       outp  = (float*)d_out;

    unsigned short* w1t = (unsigned short*)d_ws;        // 256 KB
    unsigned short* w2t = w1t + NT * 128 * 128;         // 128 KB

    convert_weights<<<dim3(512), dim3(256), 0, stream>>>(W1, W2, w1t, w2t);
    dag_encoder_kernel<<<dim3(NB), dim3(NTH), 0, stream>>>(
        roots, b1, b2, idxs, types, outp, w1t, w2t);
}